// Round 1
// baseline (756.335 us; speedup 1.0000x reference)
//
#include <hip/hip_runtime.h>

// Problem constants (match reference)
#define B_    256
#define L_    2000
#define C_    4
#define KL_   18
#define K2_   64
#define KN_   128
#define PAD_  4
#define LP_   2008           // L + 2*PAD
#define LOUT_ 1990           // LP - KL

// Tiling
#define TI_   256            // output positions per block
#define KT_   32             // k-channels per block (2 ktiles cover K2=64)
#define PSTR_ 280            // padded stride of p rows (>= TI_+KL_+6)

__device__ __forceinline__ float4 load_x4(const float* __restrict__ x, int b, int dir, int q) {
    // xp[c][q] for all 4 channels; q is padded-coordinate. m = q - PAD is the
    // index into the (possibly reversed) length-L sequence.
    int m = q - PAD_;
    if (m < 0 || m >= L_) return make_float4(0.f, 0.f, 0.f, 0.f);
    int l = dir ? (L_ - 1 - m) : m;                 // reverse = flip length dim
    const float* p = x + ((size_t)b * L_ + l) * C_; // [B,L,C] channel-last, 16B aligned
    return *reinterpret_cast<const float4*>(p);
}

__global__ __launch_bounds__(256, 2)
void markonv_fp32(const float* __restrict__ x,
                  const float* __restrict__ Wf,
                  const float* __restrict__ Wr,
                  const float* __restrict__ kwf,
                  const float* __restrict__ kwr,
                  float* __restrict__ out) {
    __shared__ float p_lds[16][PSTR_];        // 17.9 KB  pair-products
    __shared__ float wm_lds[KL_][16][KT_];    // 36.9 KB  masked weights tile
    __shared__ float m_lds[KL_][KT_];         //  2.3 KB  mask

    const int tid   = threadIdx.x;
    const int itile = blockIdx.x;             // 0..7
    const int b     = blockIdx.y;             // 0..255
    const int z     = blockIdx.z;             // 0..3
    const int dir   = z >> 1;                 // 0 fwd, 1 rev
    const int ktile = z & 1;                  // 0/1 -> k in [0,32) / [32,64)
    const int i0    = itile * TI_;

    const float* W  = dir ? Wr  : Wf;
    const float* kw = dir ? kwr : kwf;

    // ---- mask: m[j,k] = sig(j - kw0[k]) + sig(kw1[k] - j) - 1 ----
    for (int t = tid; t < KL_ * KT_; t += 256) {
        int j  = t / KT_;
        int kk = t % KT_;
        int k  = ktile * KT_ + kk;
        float kw0 = kw[k];
        float kw1 = kw[K2_ + k];
        float s0 = 1.f / (1.f + expf(-((float)j - kw0)));
        float s1 = 1.f / (1.f + expf(-(kw1 - (float)j)));
        m_lds[j][kk] = s0 + s1 - 1.f;
    }
    __syncthreads();

    // ---- masked weight tile: wm[j][cd][kk] = W[j,c,d,k]*m[j,k] ----
    for (int t = tid; t < KL_ * 16 * KT_; t += 256) {
        int kk = t % KT_;
        int cd = (t / KT_) % 16;
        int j  = t / (KT_ * 16);
        wm_lds[j][cd][kk] = W[(size_t)j * (16 * K2_) + cd * K2_ + ktile * KT_ + kk] * m_lds[j][kk];
    }

    // ---- pair products p[(c,d)][li] = xp[c][i0+li] * xp[d][i0+li+1] ----
    for (int li = tid; li < TI_ + KL_; li += 256) {   // 274 positions
        int q = i0 + li;
        float4 xa = load_x4(x, b, dir, q);
        float4 xb = load_x4(x, b, dir, q + 1);
        float va[4] = {xa.x, xa.y, xa.z, xa.w};
        float vb[4] = {xb.x, xb.y, xb.z, xb.w};
        #pragma unroll
        for (int c = 0; c < 4; ++c)
            #pragma unroll
            for (int d = 0; d < 4; ++d)
                p_lds[c * 4 + d][li] = va[c] * vb[d];
    }
    __syncthreads();

    // ---- main compute ----
    // wave owns 8 consecutive k (wave-uniform -> LDS broadcast reads of W);
    // lane owns 4 consecutive output positions.
    const int wave  = tid >> 6;          // 0..3
    const int lane  = tid & 63;
    const int kbase = wave * 8;          // within KT_
    const int ibase = lane * 4;          // within TI_

    float acc[8][4];
    #pragma unroll
    for (int kk = 0; kk < 8; ++kk)
        #pragma unroll
        for (int r = 0; r < 4; ++r) acc[kk][r] = 0.f;

    for (int cd = 0; cd < 16; ++cd) {
        // register run of p: positions ibase .. ibase+20 used (load 24, 16B-aligned)
        float run[24];
        const float4* pr = reinterpret_cast<const float4*>(&p_lds[cd][ibase]);
        #pragma unroll
        for (int v = 0; v < 6; ++v) {
            float4 t = pr[v];
            run[4 * v + 0] = t.x; run[4 * v + 1] = t.y;
            run[4 * v + 2] = t.z; run[4 * v + 3] = t.w;
        }
        #pragma unroll
        for (int j = 0; j < KL_; ++j) {
            const float4* wp = reinterpret_cast<const float4*>(&wm_lds[j][cd][kbase]);
            float4 w0 = wp[0], w1 = wp[1];
            float wv[8] = {w0.x, w0.y, w0.z, w0.w, w1.x, w1.y, w1.z, w1.w};
            #pragma unroll
            for (int kk = 0; kk < 8; ++kk)
                #pragma unroll
                for (int r = 0; r < 4; ++r)
                    acc[kk][r] = fmaf(wv[kk], run[j + r], acc[kk][r]);
        }
    }

    // ---- store: out[b, dir*64 + ktile*32 + kbase + kk, i0 + ibase + r] ----
    const int kg = ktile * KT_ + kbase;
    const int gi = i0 + ibase;
    float* outp = out + ((size_t)b * KN_ + (size_t)dir * K2_ + kg) * LOUT_;
    #pragma unroll
    for (int kk = 0; kk < 8; ++kk) {
        size_t row = (size_t)kk * LOUT_ + gi;
        #pragma unroll
        for (int r = 0; r < 4; r += 2) {
            if (gi + r + 1 < LOUT_) {
                *reinterpret_cast<float2*>(&outp[row + r]) = make_float2(acc[kk][r], acc[kk][r + 1]);
            } else if (gi + r < LOUT_) {
                outp[row + r] = acc[kk][r];
            }
        }
    }
}

extern "C" void kernel_launch(void* const* d_in, const int* in_sizes, int n_in,
                              void* d_out, int out_size, void* d_ws, size_t ws_size,
                              hipStream_t stream) {
    const float* x   = (const float*)d_in[0];
    const float* Wf  = (const float*)d_in[1];
    const float* Wr  = (const float*)d_in[2];
    const float* kwf = (const float*)d_in[3];
    const float* kwr = (const float*)d_in[4];
    float* out = (float*)d_out;

    dim3 grid(8 /*itiles: 8*256 >= 1990*/, B_, 4 /*dir x ktile*/);
    markonv_fp32<<<grid, 256, 0, stream>>>(x, Wf, Wr, kwf, kwr, out);
}

// Round 2
// 321.642 us; speedup vs baseline: 2.3515x; 2.3515x over previous
//
#include <hip/hip_runtime.h>

// Problem constants
#define B_    256
#define L_    2000
#define KL_   18
#define K2_   64
#define KN_   128
#define PAD_  4
#define LOUT_ 1990

// Tiling
#define TI_   256            // output positions per block
#define NPOS_ 274            // TI_ + KL_ p-rows needed per block
#define PSTR_ 24             // bf16 per p-row (48B): 16B-aligned halves, full bank rotation

typedef __attribute__((ext_vector_type(8)))  short bf16x8;
typedef __attribute__((ext_vector_type(16))) float f32x16;

__device__ __forceinline__ unsigned short f2bf(float f) {
    unsigned u = __float_as_uint(f);
    unsigned r = (u + 0x7fffu + ((u >> 16) & 1u)) >> 16;   // RTN-even
    return (unsigned short)r;
}
__device__ __forceinline__ float bf2f(unsigned short s) {
    return __uint_as_float(((unsigned)s) << 16);
}

__device__ __forceinline__ float4 load_x4(const float* __restrict__ x, int b, int dir, int q) {
    int m = q - PAD_;
    if (m < 0 || m >= L_) return make_float4(0.f, 0.f, 0.f, 0.f);
    int l = dir ? (L_ - 1 - m) : m;
    const float* p = x + ((size_t)b * L_ + l) * 4;   // [B,L,C] channel-last
    return *reinterpret_cast<const float4*>(p);
}

__global__ __launch_bounds__(256, 2)
void markonv_mfma(const float* __restrict__ x,
                  const float* __restrict__ Wf,
                  const float* __restrict__ Wr,
                  const float* __restrict__ kwf,
                  const float* __restrict__ kwr,
                  float* __restrict__ out) {
    // p split into hi/lo bf16, position-major, stride 24 bf16 (48B)
    __shared__ __align__(16) unsigned short phi[NPOS_ * PSTR_];   // 13.2 KB
    __shared__ __align__(16) unsigned short plo[NPOS_ * PSTR_];   // 13.2 KB

    const int tid   = threadIdx.x;
    const int itile = blockIdx.x;            // 0..7
    const int b     = blockIdx.y;            // 0..255
    const int dir   = blockIdx.z;            // 0..1
    const int i0    = itile * TI_;

    const float* W  = dir ? Wr  : Wf;
    const float* kw = dir ? kwr : kwf;

    const int wave   = tid >> 6;
    const int lane   = tid & 63;
    const int kgroup = wave & 1;             // which 32-k half of K2=64
    const int col    = lane & 31;            // MFMA col / A row
    const int cd0    = (lane >> 5) * 8;      // contract half: cd 0..7 or 8..15
    const int kglob  = kgroup * 32 + col;    // this lane's output channel (A row)

    // ---- A-fragments: masked weights, one bf16x8 per tap j (72 VGPR) ----
    float kw0 = kw[kglob];
    float kw1 = kw[K2_ + kglob];
    bf16x8 af[KL_];
    #pragma unroll
    for (int j = 0; j < KL_; ++j) {
        float fj = (float)j;
        float m = 1.f / (1.f + __expf(-(fj - kw0)))
                + 1.f / (1.f + __expf(-(kw1 - fj))) - 1.f;
        #pragma unroll
        for (int e = 0; e < 8; ++e) {
            // A[row=k][r=j*16+cd] = W[j, cd, k] * mask[j,k]; lanes 0-31/32-63 take cd halves.
            float wv = W[(size_t)(j * 16 + cd0 + e) * K2_ + kglob] * m;
            af[j][e] = (short)f2bf(wv);
        }
    }

    // ---- build pair-products p[pos][cd], split hi/lo ----
    for (int li = tid; li < NPOS_; li += 256) {
        int q = i0 + li;
        float4 xa = load_x4(x, b, dir, q);
        float4 xb = load_x4(x, b, dir, q + 1);
        float va[4] = {xa.x, xa.y, xa.z, xa.w};
        float vb[4] = {xb.x, xb.y, xb.z, xb.w};
        unsigned short hi[16], lo[16];
        #pragma unroll
        for (int c = 0; c < 4; ++c)
            #pragma unroll
            for (int d = 0; d < 4; ++d) {
                float p = va[c] * vb[d];
                unsigned short h = f2bf(p);
                hi[c * 4 + d] = h;
                lo[c * 4 + d] = f2bf(p - bf2f(h));
            }
        unsigned* ph = (unsigned*)&phi[li * PSTR_];
        unsigned* pl = (unsigned*)&plo[li * PSTR_];
        #pragma unroll
        for (int t = 0; t < 8; ++t) {
            ph[t] = (unsigned)hi[2 * t] | ((unsigned)hi[2 * t + 1] << 16);
            pl[t] = (unsigned)lo[2 * t] | ((unsigned)lo[2 * t + 1] << 16);
        }
    }
    __syncthreads();

    // ---- MFMA main: D[k(32) x i(32)] tiles, K=288 as 18 taps ----
    // wave -> (kgroup = wave&1); subtile pairs {sp,sp+1} for sp in {(wave>>1)*2, +4}
    const int sp0 = (wave >> 1) * 2;
    for (int spp = sp0; spp < 8; spp += 4) {
        const int s0 = spp, s1 = spp + 1;
        f32x16 a0, a1;
        #pragma unroll
        for (int r = 0; r < 16; ++r) { a0[r] = 0.f; a1[r] = 0.f; }

        const int r0 = (s0 * 32 + col) * PSTR_ + cd0;
        const int r1 = (s1 * 32 + col) * PSTR_ + cd0;
        #pragma unroll
        for (int j = 0; j < KL_; ++j) {
            bf16x8 b0h = *(const bf16x8*)&phi[r0 + j * PSTR_];
            bf16x8 b1h = *(const bf16x8*)&phi[r1 + j * PSTR_];
            bf16x8 b0l = *(const bf16x8*)&plo[r0 + j * PSTR_];
            bf16x8 b1l = *(const bf16x8*)&plo[r1 + j * PSTR_];
            a0 = __builtin_amdgcn_mfma_f32_32x32x16_bf16(af[j], b0h, a0, 0, 0, 0);
            a1 = __builtin_amdgcn_mfma_f32_32x32x16_bf16(af[j], b1h, a1, 0, 0, 0);
            a0 = __builtin_amdgcn_mfma_f32_32x32x16_bf16(af[j], b0l, a0, 0, 0, 0);
            a1 = __builtin_amdgcn_mfma_f32_32x32x16_bf16(af[j], b1l, a1, 0, 0, 0);
        }

        // stores: C/D layout col=lane&31, row=(r&3)+8*(r>>2)+4*(lane>>5)  [m74/m101]
        float* ob = out + ((size_t)b * KN_ + (size_t)dir * K2_ + kgroup * 32) * LOUT_;
        const int rbase = 4 * (lane >> 5);
        int ig0 = i0 + s0 * 32 + col;
        if (ig0 < LOUT_) {
            #pragma unroll
            for (int r = 0; r < 16; ++r) {
                int row = (r & 3) + 8 * (r >> 2) + rbase;
                ob[(size_t)row * LOUT_ + ig0] = a0[r];
            }
        }
        int ig1 = i0 + s1 * 32 + col;
        if (ig1 < LOUT_) {
            #pragma unroll
            for (int r = 0; r < 16; ++r) {
                int row = (r & 3) + 8 * (r >> 2) + rbase;
                ob[(size_t)row * LOUT_ + ig1] = a1[r];
            }
        }
    }
}

extern "C" void kernel_launch(void* const* d_in, const int* in_sizes, int n_in,
                              void* d_out, int out_size, void* d_ws, size_t ws_size,
                              hipStream_t stream) {
    const float* x   = (const float*)d_in[0];
    const float* Wf  = (const float*)d_in[1];
    const float* Wr  = (const float*)d_in[2];
    const float* kwf = (const float*)d_in[3];
    const float* kwr = (const float*)d_in[4];
    float* out = (float*)d_out;

    dim3 grid(8 /*itiles*/, B_, 2 /*dir*/);
    markonv_mfma<<<grid, 256, 0, stream>>>(x, Wf, Wr, kwf, kwr, out);
}